// Round 1
// baseline (33724.930 us; speedup 1.0000x reference)
//
#include <hip/hip_runtime.h>
#include <cstdint>
#include <cstddef>

// Problem constants
#define Tn 1024
#define Bn 512
#define Hn 256

// LDS strides (elements). Chosen so byte strides are odd multiples of 16B
// (bank-friendly) and all vector accesses stay 8B/16B aligned.
#define A1S 296   // [64 x 296] fp16: cols 0..9 x, 10..15 zero, 16..271 h1(t-1), 272..295 zero
#define H2S 264   // [64 x 264] fp16: cols 0..255 h2(t-2)
#define W1S 296   // [32 x 296] fp16 weights layer1 (row n=4u+g -> W row g*256+u0+u)
#define W2S 520   // [32 x 520] fp16: cols 0..255 w_ih1, 256..511 w_hh1
#define WHS 264   // [16 x 264] fp16: rows 0..7 adv_w1 slice, rows 8..15 zero
#define GSS 36    // [64 x 36] f32 gate scratch
#define HSS 20    // [64 x 20] f32 head scratch

#define A1_OFF  0
#define H2_OFF  (A1_OFF + 64*A1S*2)          // 37888
#define W1_OFF  (H2_OFF + 64*H2S*2)          // 71680
#define W2_OFF  (W1_OFF + 32*W1S*2)          // 90624
#define WH_OFF  (W2_OFF + 32*W2S*2)          // 123904
#define GS_OFF  (WH_OFF + 16*WHS*2)          // 132352
#define HS_OFF  (GS_OFF + 64*GSS*4)          // 141568
#define C1_OFF  (HS_OFF + 64*HSS*4)          // 146688
#define C2_OFF  (C1_OFF + 64*8*4)            // 148736
#define B1_OFF  (C2_OFF + 64*8*4)            // 150784
#define B2_OFF  (B1_OFF + 32*4)              // 150912
#define BH_OFF  (B2_OFF + 32*4)              // 151040
#define W2H_OFF (BH_OFF + 8*4)               // 151072
#define LDS_TOTAL (W2H_OFF + 8*4)            // 151104 bytes (<160KiB, forces 1 block/CU)

// ws layout (bytes)
#define SCORES_OFF 0                          // [1024][512] f32 = 2MB
#define H1G_OFF  (2*1024*1024)                // 4 slots x [512][256] fp16 = 1MB
#define H2G_OFF  (3*1024*1024)                // 1MB
#define FLAG_OFF (4*1024*1024)                // c1[8] at rt*32, c2[8] at (8+rt)*32
#define WS_USED  (4*1024*1024 + 4096)

typedef _Float16 v4h __attribute__((ext_vector_type(4)));
typedef float    v4f __attribute__((ext_vector_type(4)));

__device__ inline float sigm(float x){ return 1.0f/(1.0f + __expf(-x)); }
__device__ inline float tanh_f(float x){ return 1.0f - 2.0f/(1.0f + __expf(2.0f*x)); }

__global__ __launch_bounds__(512)
void lstm_pipe(const float* __restrict__ x,
               const float* __restrict__ w_ih0, const float* __restrict__ w_hh0,
               const float* __restrict__ b_ih0, const float* __restrict__ b_hh0,
               const float* __restrict__ w_ih1, const float* __restrict__ w_hh1,
               const float* __restrict__ b_ih1, const float* __restrict__ b_hh1,
               const float* __restrict__ adv_w1, const float* __restrict__ adv_b1,
               const float* __restrict__ adv_w2,
               float* __restrict__ scores, _Float16* __restrict__ h1g,
               _Float16* __restrict__ h2g, int* __restrict__ flags)
{
    extern __shared__ char smem[];
    _Float16* A1  = (_Float16*)(smem + A1_OFF);
    _Float16* H2l = (_Float16*)(smem + H2_OFF);
    _Float16* W1l = (_Float16*)(smem + W1_OFF);
    _Float16* W2l = (_Float16*)(smem + W2_OFF);
    _Float16* WHl = (_Float16*)(smem + WH_OFF);
    float* gatesc = (float*)(smem + GS_OFF);
    float* headsc = (float*)(smem + HS_OFF);
    float* c1s    = (float*)(smem + C1_OFF);
    float* c2s    = (float*)(smem + C2_OFF);
    float* b1s    = (float*)(smem + B1_OFF);
    float* b2s    = (float*)(smem + B2_OFF);
    float* bhs    = (float*)(smem + BH_OFF);
    float* w2hs   = (float*)(smem + W2H_OFF);

    const int tid  = threadIdx.x;
    const int lane = tid & 63;
    const int wv   = tid >> 6;
    const int rt = blockIdx.x >> 5;        // 0..7  (64-row tile)
    const int us = blockIdx.x & 31;        // 0..31 (8-unit slice)
    const int r0 = rt * 64;
    const int u0 = us * 8;

    // ---- one-time weight preload into LDS (fp16) ----
    for (int idx = tid; idx < 32*W1S; idx += 512){
        int n = idx / W1S, c = idx - n*W1S;
        int g = n & 3, du = n >> 2;
        int R = g*256 + u0 + du;
        float v = 0.f;
        if (c < 10) v = w_ih0[R*10 + c];
        else if (c >= 16 && c < 272) v = w_hh0[R*256 + (c-16)];
        W1l[idx] = (_Float16)v;
    }
    for (int idx = tid; idx < 32*W2S; idx += 512){
        int n = idx / W2S, c = idx - n*W2S;
        int g = n & 3, du = n >> 2;
        int R = g*256 + u0 + du;
        float v = (c < 256) ? w_ih1[R*256 + c] :
                  ((c < 512) ? w_hh1[R*256 + (c-256)] : 0.f);
        W2l[idx] = (_Float16)v;
    }
    for (int idx = tid; idx < 16*WHS; idx += 512){
        int n = idx / WHS, c = idx - n*WHS;
        float v = 0.f;
        if (n < 8 && c < 256) v = adv_w1[(u0+n)*256 + c];
        WHl[idx] = (_Float16)v;
    }
    if (tid < 32){
        int g = tid & 3, du = tid >> 2;
        int R = g*256 + u0 + du;
        b1s[tid] = b_ih0[R] + b_hh0[R];
        b2s[tid] = b_ih1[R] + b_hh1[R];
    }
    if (tid < 8){
        bhs[tid]  = adv_b1[u0 + tid];
        w2hs[tid] = adv_w2[u0 + tid];
    }
    c1s[tid] = 0.f;     // 64x8 == 512 exactly
    c2s[tid] = 0.f;
    // zero A1 pad columns (10..15, 272..295), constant for the whole loop
    for (int idx = tid; idx < 64*30; idx += 512){
        int row = idx / 30, j = idx - row*30;
        int c = (j < 6) ? (10 + j) : (272 + (j - 6));
        A1[row*A1S + c] = (_Float16)0.f;
    }
    __syncthreads();

    const int c1idx = rt*32;
    const int c2idx = (8 + rt)*32;

    for (int tau = 0; tau <= Tn + 1; ++tau){
        // ---- acquire: wait for producers of h1(tau-1) / h2(tau-2) ----
        if (tid == 0){
            if (tau >= 1 && tau <= Tn){
                int tgt = 32*tau;
                while (__hip_atomic_load(&flags[c1idx], __ATOMIC_RELAXED,
                                         __HIP_MEMORY_SCOPE_AGENT) < tgt)
                    __builtin_amdgcn_s_sleep(2);
            }
            if (tau >= 2){
                int tgt = 32*(tau-1);
                while (__hip_atomic_load(&flags[c2idx], __ATOMIC_RELAXED,
                                         __HIP_MEMORY_SCOPE_AGENT) < tgt)
                    __builtin_amdgcn_s_sleep(2);
            }
        }
        __syncthreads();
        __builtin_amdgcn_fence(__ATOMIC_ACQUIRE, "agent");

        // ---- stage inputs into LDS ----
        if (tau <= Tn){   // h1(tau-1), slot (tau-1)&3
            int slot = (tau + 3) & 3;
            int row = tid >> 3, seg = tid & 7;
            const int4* src = (const int4*)(h1g + (size_t)slot*(Bn*Hn) + (r0+row)*Hn + seg*32);
            int4* dst = (int4*)(A1 + row*A1S + 16 + seg*32);
            #pragma unroll
            for (int i = 0; i < 4; ++i) dst[i] = src[i];
        }
        if (tau < Tn && tid < 64){   // x(tau)
            const float* xp = x + ((size_t)(r0 + tid)*Tn + tau)*10;
            #pragma unroll
            for (int i = 0; i < 10; ++i) A1[tid*A1S + i] = (_Float16)xp[i];
        }
        if (tau >= 1){   // h2(tau-2), slot (tau-2)&3
            int slot = (tau + 2) & 3;
            int row = tid >> 3, seg = tid & 7;
            const int4* src = (const int4*)(h2g + (size_t)slot*(Bn*Hn) + (r0+row)*Hn + seg*32);
            int4* dst = (int4*)(H2l + row*H2S + seg*32);
            #pragma unroll
            for (int i = 0; i < 4; ++i) dst[i] = src[i];
        }
        __syncthreads();

        // ---- G1(tau): gates1[64x32] = [x|h1] @ W1^T, K=288 ----
        if (tau < Tn){
            int mt = wv & 3, nt = wv >> 2;
            v4f acc = {0.f, 0.f, 0.f, 0.f};
            const _Float16* Ap = A1 + (mt*16 + (lane & 15))*A1S + ((lane >> 4)*4);
            const _Float16* Bp = W1l + (nt*16 + (lane & 15))*W1S + ((lane >> 4)*4);
            #pragma unroll
            for (int k = 0; k < 18; ++k){
                v4h a = *(const v4h*)(Ap + k*16);
                v4h b = *(const v4h*)(Bp + k*16);
                acc = __builtin_amdgcn_mfma_f32_16x16x16f16(a, b, acc, 0, 0, 0);
            }
            #pragma unroll
            for (int r = 0; r < 4; ++r)
                gatesc[(mt*16 + (lane>>4)*4 + r)*GSS + nt*16 + (lane & 15)] = acc[r];
        }
        // ---- head(tau-2): hidden[64x8(+8 pad)] = h2(tau-2) @ advW1^T, waves 0..3 ----
        if (tau >= 2 && wv < 4){
            int mt = wv;
            v4f acc = {0.f, 0.f, 0.f, 0.f};
            const _Float16* Ap = H2l + (mt*16 + (lane & 15))*H2S + ((lane >> 4)*4);
            const _Float16* Bp = WHl + (lane & 15)*WHS + ((lane >> 4)*4);
            #pragma unroll
            for (int k = 0; k < 16; ++k){
                v4h a = *(const v4h*)(Ap + k*16);
                v4h b = *(const v4h*)(Bp + k*16);
                acc = __builtin_amdgcn_mfma_f32_16x16x16f16(a, b, acc, 0, 0, 0);
            }
            #pragma unroll
            for (int r = 0; r < 4; ++r)
                headsc[(mt*16 + (lane>>4)*4 + r)*HSS + (lane & 15)] = acc[r];
        }
        __syncthreads();

        // ---- elementwise layer1 update + head finalize ----
        if (tau < Tn){
            int row = tid >> 3, u = tid & 7;
            v4f g4 = *(const v4f*)(gatesc + row*GSS + 4*u);
            v4f bb = *(const v4f*)(b1s + 4*u);
            float gi = sigm(g4.x + bb.x);
            float gf = sigm(g4.y + bb.y);
            float gg = tanh_f(g4.z + bb.z);
            float go = sigm(g4.w + bb.w);
            float c  = c1s[tid];
            float cn = gf*c + gi*gg;
            float hn = go * tanh_f(cn);
            c1s[tid] = cn;
            h1g[(size_t)(tau & 3)*(Bn*Hn) + (r0+row)*Hn + (u0+u)] = (_Float16)hn;
        }
        if (tau >= 2 && tid < 64){
            float s = 0.f;
            #pragma unroll
            for (int u = 0; u < 8; ++u){
                float hv = headsc[tid*HSS + u] + bhs[u];
                s += fmaxf(hv, 0.f) * w2hs[u];
            }
            atomicAdd(&scores[(size_t)(tau - 2)*Bn + r0 + tid], s);
        }
        __syncthreads();   // h1 stores drained (barrier implies vmcnt(0))
        if (tau < Tn && tid == 0)
            (void)__hip_atomic_fetch_add(&flags[c1idx], 1, __ATOMIC_RELEASE,
                                         __HIP_MEMORY_SCOPE_AGENT);

        // ---- G2(tau-1): gates2[64x32] = [h1(tau-1)|h2(tau-2)] @ W2^T, K=512 ----
        if (tau >= 1 && tau <= Tn){
            int mt = wv & 3, nt = wv >> 2;
            v4f acc = {0.f, 0.f, 0.f, 0.f};
            const _Float16* Ap1 = A1  + (mt*16 + (lane & 15))*A1S + 16 + ((lane >> 4)*4);
            const _Float16* Ap2 = H2l + (mt*16 + (lane & 15))*H2S + ((lane >> 4)*4);
            const _Float16* Bp  = W2l + (nt*16 + (lane & 15))*W2S + ((lane >> 4)*4);
            #pragma unroll
            for (int k = 0; k < 16; ++k){
                v4h a = *(const v4h*)(Ap1 + k*16);
                v4h b = *(const v4h*)(Bp + k*16);
                acc = __builtin_amdgcn_mfma_f32_16x16x16f16(a, b, acc, 0, 0, 0);
            }
            #pragma unroll
            for (int k = 0; k < 16; ++k){
                v4h a = *(const v4h*)(Ap2 + k*16);
                v4h b = *(const v4h*)(Bp + 256 + k*16);
                acc = __builtin_amdgcn_mfma_f32_16x16x16f16(a, b, acc, 0, 0, 0);
            }
            #pragma unroll
            for (int r = 0; r < 4; ++r)
                gatesc[(mt*16 + (lane>>4)*4 + r)*GSS + nt*16 + (lane & 15)] = acc[r];
        }
        __syncthreads();
        if (tau >= 1 && tau <= Tn){
            int row = tid >> 3, u = tid & 7;
            v4f g4 = *(const v4f*)(gatesc + row*GSS + 4*u);
            v4f bb = *(const v4f*)(b2s + 4*u);
            float gi = sigm(g4.x + bb.x);
            float gf = sigm(g4.y + bb.y);
            float gg = tanh_f(g4.z + bb.z);
            float go = sigm(g4.w + bb.w);
            float c  = c2s[tid];
            float cn = gf*c + gi*gg;
            float hn = go * tanh_f(cn);
            c2s[tid] = cn;
            h2g[(size_t)((tau + 3) & 3)*(Bn*Hn) + (r0+row)*Hn + (u0+u)] = (_Float16)hn;
        }
        __syncthreads();
        if (tau >= 1 && tau <= Tn && tid == 0)
            (void)__hip_atomic_fetch_add(&flags[c2idx], 1, __ATOMIC_RELEASE,
                                         __HIP_MEMORY_SCOPE_AGENT);
    }
}

// mixed[b] = scores.flat[b*1024 .. b*1024+1023]  (time-major flatten == contiguous)
__global__ __launch_bounds__(256)
void softmax_adv(const float* __restrict__ scores, float* __restrict__ out)
{
    const int b = blockIdx.x, tid = threadIdx.x;
    const int lane = tid & 63, wv = tid >> 6;
    __shared__ float red[4];
    const float4* sp = (const float4*)(scores + (size_t)b*1024);
    float4 v = sp[tid];
    float m = fmaxf(fmaxf(v.x, v.y), fmaxf(v.z, v.w));
    #pragma unroll
    for (int o = 32; o > 0; o >>= 1) m = fmaxf(m, __shfl_xor(m, o, 64));
    if (lane == 0) red[wv] = m;
    __syncthreads();
    m = fmaxf(fmaxf(red[0], red[1]), fmaxf(red[2], red[3]));
    __syncthreads();
    float e0 = __expf(v.x - m), e1 = __expf(v.y - m);
    float e2 = __expf(v.z - m), e3 = __expf(v.w - m);
    float s = e0 + e1 + e2 + e3;
    #pragma unroll
    for (int o = 32; o > 0; o >>= 1) s += __shfl_xor(s, o, 64);
    if (lane == 0) red[wv] = s;
    __syncthreads();
    s = red[0] + red[1] + red[2] + red[3];
    float inv = 1.0f / s;
    float4 o4; o4.x = e0*inv; o4.y = e1*inv; o4.z = e2*inv; o4.w = e3*inv;
    ((float4*)(out + (size_t)b*1024))[tid] = o4;
}

extern "C" void kernel_launch(void* const* d_in, const int* in_sizes, int n_in,
                              void* d_out, int out_size, void* d_ws, size_t ws_size,
                              hipStream_t stream)
{
    (void)in_sizes; (void)n_in; (void)out_size; (void)ws_size;
    const float* x      = (const float*)d_in[0];
    const float* w_ih0  = (const float*)d_in[1];
    const float* w_hh0  = (const float*)d_in[2];
    const float* b_ih0  = (const float*)d_in[3];
    const float* b_hh0  = (const float*)d_in[4];
    const float* w_ih1  = (const float*)d_in[5];
    const float* w_hh1  = (const float*)d_in[6];
    const float* b_ih1  = (const float*)d_in[7];
    const float* b_hh1  = (const float*)d_in[8];
    const float* adv_w1 = (const float*)d_in[9];
    const float* adv_b1 = (const float*)d_in[10];
    const float* adv_w2 = (const float*)d_in[11];
    // adv_w2 bias (d_in[12]) cancels in softmax — unused.

    float*    scores = (float*)((char*)d_ws + SCORES_OFF);
    _Float16* h1g    = (_Float16*)((char*)d_ws + H1G_OFF);
    _Float16* h2g    = (_Float16*)((char*)d_ws + H2G_OFF);
    int*      flags  = (int*)((char*)d_ws + FLAG_OFF);

    hipMemsetAsync(d_ws, 0, WS_USED, stream);
    hipFuncSetAttribute((const void*)lstm_pipe,
                        hipFuncAttributeMaxDynamicSharedMemorySize, LDS_TOTAL);

    hipLaunchKernelGGL(lstm_pipe, dim3(256), dim3(512), LDS_TOTAL, stream,
                       x, w_ih0, w_hh0, b_ih0, b_hh0, w_ih1, w_hh1, b_ih1, b_hh1,
                       adv_w1, adv_b1, adv_w2, scores, h1g, h2g, flags);
    hipLaunchKernelGGL(softmax_adv, dim3(512), dim3(256), 0, stream,
                       scores, (float*)d_out);
}

// Round 2
// 8082.384 us; speedup vs baseline: 4.1726x; 4.1726x over previous
//
#include <hip/hip_runtime.h>
#include <cstdint>
#include <cstddef>

// Problem constants
#define Tn 1024
#define Bn 512
#define Hn 256

// LDS strides (fp16 elements)
#define A1S 296   // [64 x 296]: cols 0..9 x, 10..15 zero, 16..271 h1(t-1), 272.. pad
#define H2S 264   // [64 x 264]: cols 0..255 h2(t-2)
#define W1S 296   // [32 x 296] layer1 weights (row n -> W row (n&3)*256+u0+(n>>2))
#define W2S 520   // [32 x 520]: cols 0..255 w_ih1, 256..511 w_hh1
#define WHS 264   // [16 x 264]: rows 0..7 adv_w1 slice, 8..15 zero
#define GSS 36    // [64 x 36] f32 gate scratch
#define HSS 20    // [64 x 20] f32 head scratch

#define A1_OFF  0
#define H2_OFF  (A1_OFF + 64*A1S*2)
#define W1_OFF  (H2_OFF + 64*H2S*2)
#define W2_OFF  (W1_OFF + 32*W1S*2)
#define WH_OFF  (W2_OFF + 32*W2S*2)
#define GS_OFF  (WH_OFF + 16*WHS*2)
#define HS_OFF  (GS_OFF + 64*GSS*4)
#define C1_OFF  (HS_OFF + 64*HSS*4)
#define C2_OFF  (C1_OFF + 64*8*4)
#define B1_OFF  (C2_OFF + 64*8*4)
#define B2_OFF  (B1_OFF + 32*4)
#define BH_OFF  (B2_OFF + 32*4)
#define W2H_OFF (BH_OFF + 8*4)
#define HST_OFF (W2H_OFF + 8*4)              // h staging for packed publish: 64*8 fp16
#define LDS_TOTAL (HST_OFF + 64*8*2)         // 152128 B (<160KiB, forces 1 block/CU)

// ws layout (bytes)
#define SCORES_OFF 0                          // [1024][512] f32 = 2MB
#define H1G_OFF  (2*1024*1024)                // 4 slots x [512][256] fp16 = 1MB
#define H2G_OFF  (3*1024*1024)                // 1MB
#define FLAG_OFF (4*1024*1024)                // c1[8] at rt*32, c2[8] at (8+rt)*32
#define WS_USED  (4*1024*1024 + 4096)

typedef _Float16 v4h __attribute__((ext_vector_type(4)));
typedef float    v4f __attribute__((ext_vector_type(4)));
typedef unsigned long long u64;

__device__ inline float sigm(float x){ return 1.0f/(1.0f + __expf(-x)); }
__device__ inline float tanh_f(float x){ return 1.0f - 2.0f/(1.0f + __expf(2.0f*x)); }

__global__ __launch_bounds__(512)
void lstm_pipe(const float* __restrict__ x,
               const float* __restrict__ w_ih0, const float* __restrict__ w_hh0,
               const float* __restrict__ b_ih0, const float* __restrict__ b_hh0,
               const float* __restrict__ w_ih1, const float* __restrict__ w_hh1,
               const float* __restrict__ b_ih1, const float* __restrict__ b_hh1,
               const float* __restrict__ adv_w1, const float* __restrict__ adv_b1,
               const float* __restrict__ adv_w2,
               float* __restrict__ scores, _Float16* __restrict__ h1g,
               _Float16* __restrict__ h2g, int* __restrict__ flags)
{
    extern __shared__ char smem[];
    _Float16* A1  = (_Float16*)(smem + A1_OFF);
    _Float16* H2l = (_Float16*)(smem + H2_OFF);
    _Float16* W1l = (_Float16*)(smem + W1_OFF);
    _Float16* W2l = (_Float16*)(smem + W2_OFF);
    _Float16* WHl = (_Float16*)(smem + WH_OFF);
    float* gatesc = (float*)(smem + GS_OFF);
    float* headsc = (float*)(smem + HS_OFF);
    float* c1s    = (float*)(smem + C1_OFF);
    float* c2s    = (float*)(smem + C2_OFF);
    float* b1s    = (float*)(smem + B1_OFF);
    float* b2s    = (float*)(smem + B2_OFF);
    float* bhs    = (float*)(smem + BH_OFF);
    float* w2hs   = (float*)(smem + W2H_OFF);
    _Float16* hstage = (_Float16*)(smem + HST_OFF);

    const int tid  = threadIdx.x;
    const int lane = tid & 63;
    const int wv   = tid >> 6;
    const int ln15 = lane & 15;
    const int ln4  = lane >> 4;
    const int rt = blockIdx.x >> 5;        // 0..7  (64-row tile)
    const int us = blockIdx.x & 31;        // 0..31 (8-unit slice)
    const int r0 = rt * 64;
    const int u0 = us * 8;
    const int mt = wv & 3, nt = wv >> 2;   // MFMA tile assignment (G1/G2)

    // ---- one-time weight preload into LDS (fp16) ----
    for (int idx = tid; idx < 32*W1S; idx += 512){
        int n = idx / W1S, c = idx - n*W1S;
        int g = n & 3, du = n >> 2;
        int R = g*256 + u0 + du;
        float v = 0.f;
        if (c < 10) v = w_ih0[R*10 + c];
        else if (c >= 16 && c < 272) v = w_hh0[R*256 + (c-16)];
        W1l[idx] = (_Float16)v;
    }
    for (int idx = tid; idx < 32*W2S; idx += 512){
        int n = idx / W2S, c = idx - n*W2S;
        int g = n & 3, du = n >> 2;
        int R = g*256 + u0 + du;
        float v = (c < 256) ? w_ih1[R*256 + c] :
                  ((c < 512) ? w_hh1[R*256 + (c-256)] : 0.f);
        W2l[idx] = (_Float16)v;
    }
    for (int idx = tid; idx < 16*WHS; idx += 512){
        int n = idx / WHS, c = idx - n*WHS;
        float v = 0.f;
        if (n < 8 && c < 256) v = adv_w1[(u0+n)*256 + c];
        WHl[idx] = (_Float16)v;
    }
    if (tid < 32){
        int g = tid & 3, du = tid >> 2;
        int R = g*256 + u0 + du;
        b1s[tid] = b_ih0[R] + b_hh0[R];
        b2s[tid] = b_ih1[R] + b_hh1[R];
    }
    if (tid < 8){
        bhs[tid]  = adv_b1[u0 + tid];
        w2hs[tid] = adv_w2[u0 + tid];
    }
    c1s[tid] = 0.f;
    c2s[tid] = 0.f;
    // zero A1 pad columns (constant for the whole loop)
    for (int idx = tid; idx < 64*30; idx += 512){
        int row = idx / 30, j = idx - row*30;
        int c = (j < 6) ? (10 + j) : (272 + (j - 6));
        A1[row*A1S + c] = (_Float16)0.f;
    }
    // stage x(0) directly (prefetch pipeline covers t>=1)
    if (tid < 64){
        const float* xp = x + ((size_t)(r0 + tid)*Tn + 0)*10;
        #pragma unroll
        for (int i = 0; i < 10; ++i) A1[tid*A1S + i] = (_Float16)xp[i];
    }
    __syncthreads();

    // ---- cache weight B-fragments in registers (loop-invariant) ----
    v4h wb1[18], wb2[32];
    {
        const _Float16* Bp1 = W1l + (nt*16 + ln15)*W1S + ln4*4;
        #pragma unroll
        for (int k = 0; k < 18; ++k) wb1[k] = *(const v4h*)(Bp1 + k*16);
        const _Float16* Bp2 = W2l + (nt*16 + ln15)*W2S + ln4*4;
        #pragma unroll
        for (int k = 0; k < 16; ++k){
            wb2[k]    = *(const v4h*)(Bp2 + k*16);
            wb2[16+k] = *(const v4h*)(Bp2 + 256 + k*16);
        }
    }

    const int c1idx = rt*32;
    const int c2idx = (8 + rt)*32;

    for (int tau = 0; tau <= Tn + 1; ++tau){
        // ===== phase A: prefetch x(tau+1); per-wave poll c1; stage h1(tau-1) =====
        float xr[10];
        if (tau + 1 < Tn && wv == 2){
            const float* xp = x + ((size_t)(r0 + lane)*Tn + (tau+1))*10;
            #pragma unroll
            for (int i = 0; i < 10; ++i) xr[i] = xp[i];
        }
        if (tau >= 1 && tau <= Tn && lane == 0){
            int tgt = 64*tau;
            while (__hip_atomic_load(&flags[c1idx], __ATOMIC_RELAXED,
                                     __HIP_MEMORY_SCOPE_AGENT) < tgt)
                __builtin_amdgcn_s_sleep(1);
        }
        asm volatile("" ::: "memory");
        if (tau <= Tn){
            int slot = (tau + 3) & 3;            // (tau-1) & 3
            int row = tid >> 3, seg = tid & 7;
            const _Float16* g = h1g + (size_t)slot*(Bn*Hn) + (size_t)(r0+row)*Hn + seg*32;
            _Float16* l = A1 + row*A1S + 16 + seg*32;
            u64 t0[8];
            #pragma unroll
            for (int j = 0; j < 8; ++j)
                t0[j] = __hip_atomic_load((const u64*)g + j, __ATOMIC_RELAXED,
                                          __HIP_MEMORY_SCOPE_AGENT);
            #pragma unroll
            for (int j = 0; j < 8; ++j) ((u64*)l)[j] = t0[j];
        }
        __syncthreads();

        // ===== phase B: G1(tau) =====
        if (tau < Tn){
            v4f acc = {0.f,0.f,0.f,0.f};
            const _Float16* Ap = A1 + (mt*16 + ln15)*A1S + ln4*4;
            #pragma unroll
            for (int k = 0; k < 18; ++k)
                acc = __builtin_amdgcn_mfma_f32_16x16x16f16(*(const v4h*)(Ap + k*16),
                                                            wb1[k], acc, 0, 0, 0);
            #pragma unroll
            for (int r = 0; r < 4; ++r)
                gatesc[(mt*16 + ln4*4 + r)*GSS + nt*16 + ln15] = acc[r];
        }
        __syncthreads();

        // ===== phase C: EW1 -> hstage; write prefetched x(tau+1) =====
        if (tau < Tn){
            int row = tid >> 3, u = tid & 7;
            v4f g4 = *(const v4f*)(gatesc + row*GSS + 4*u);
            v4f bb = *(const v4f*)(b1s + 4*u);
            float gi = sigm(g4.x + bb.x);
            float gf = sigm(g4.y + bb.y);
            float gg = tanh_f(g4.z + bb.z);
            float go = sigm(g4.w + bb.w);
            float c  = c1s[tid];
            float cn = gf*c + gi*gg;
            float hn = go * tanh_f(cn);
            c1s[tid] = cn;
            hstage[tid] = (_Float16)hn;      // tid == row*8+u
        }
        if (tau + 1 < Tn && wv == 2){
            _Float16* dst = A1 + lane*A1S;
            #pragma unroll
            for (int i = 0; i < 10; ++i) dst[i] = (_Float16)xr[i];
        }
        __syncthreads();

        // ===== phase D: publish h1(tau) (waves 0,1) + flag; poll c2; stage h2(tau-2) =====
        if (tau < Tn && wv < 2){
            int slot = tau & 3;
            int row = tid >> 1, off = (tid & 1)*4;
            u64 v = *((const u64*)hstage + tid);
            __hip_atomic_store((u64*)(h1g + (size_t)slot*(Bn*Hn) + (size_t)(r0+row)*Hn + u0 + off),
                               v, __ATOMIC_RELAXED, __HIP_MEMORY_SCOPE_AGENT);
            __builtin_amdgcn_s_waitcnt(0);
            asm volatile("" ::: "memory");
            if (lane == 0)
                (void)__hip_atomic_fetch_add(&flags[c1idx], 1, __ATOMIC_RELAXED,
                                             __HIP_MEMORY_SCOPE_AGENT);
        }
        if (tau >= 2 && lane == 0){
            int tgt = 64*(tau-1);
            while (__hip_atomic_load(&flags[c2idx], __ATOMIC_RELAXED,
                                     __HIP_MEMORY_SCOPE_AGENT) < tgt)
                __builtin_amdgcn_s_sleep(1);
        }
        asm volatile("" ::: "memory");
        if (tau >= 1){
            int slot = (tau + 2) & 3;            // (tau-2) & 3
            int row = tid >> 3, seg = tid & 7;
            const _Float16* g = h2g + (size_t)slot*(Bn*Hn) + (size_t)(r0+row)*Hn + seg*32;
            _Float16* l = H2l + row*H2S + seg*32;
            u64 t0[8];
            #pragma unroll
            for (int j = 0; j < 8; ++j)
                t0[j] = __hip_atomic_load((const u64*)g + j, __ATOMIC_RELAXED,
                                          __HIP_MEMORY_SCOPE_AGENT);
            #pragma unroll
            for (int j = 0; j < 8; ++j) ((u64*)l)[j] = t0[j];
        }
        __syncthreads();

        // ===== phase E: G2(tau-1); head(tau-2) on waves 4..7 =====
        if (tau >= 1 && tau <= Tn){
            v4f acc = {0.f,0.f,0.f,0.f};
            const _Float16* Ap1 = A1  + (mt*16 + ln15)*A1S + 16 + ln4*4;
            const _Float16* Ap2 = H2l + (mt*16 + ln15)*H2S + ln4*4;
            #pragma unroll
            for (int k = 0; k < 16; ++k)
                acc = __builtin_amdgcn_mfma_f32_16x16x16f16(*(const v4h*)(Ap1 + k*16),
                                                            wb2[k], acc, 0, 0, 0);
            #pragma unroll
            for (int k = 0; k < 16; ++k)
                acc = __builtin_amdgcn_mfma_f32_16x16x16f16(*(const v4h*)(Ap2 + k*16),
                                                            wb2[16+k], acc, 0, 0, 0);
            #pragma unroll
            for (int r = 0; r < 4; ++r)
                gatesc[(mt*16 + ln4*4 + r)*GSS + nt*16 + ln15] = acc[r];
        }
        if (tau >= 2 && wv >= 4){
            int mth = wv - 4;
            v4f acc = {0.f,0.f,0.f,0.f};
            const _Float16* Ap = H2l + (mth*16 + ln15)*H2S + ln4*4;
            const _Float16* Bp = WHl + ln15*WHS + ln4*4;
            #pragma unroll
            for (int k = 0; k < 16; ++k)
                acc = __builtin_amdgcn_mfma_f32_16x16x16f16(*(const v4h*)(Ap + k*16),
                                                            *(const v4h*)(Bp + k*16),
                                                            acc, 0, 0, 0);
            #pragma unroll
            for (int r = 0; r < 4; ++r)
                headsc[(mth*16 + ln4*4 + r)*HSS + ln15] = acc[r];
        }
        __syncthreads();

        // ===== phase F: EW2 -> hstage; head finalize -> scores =====
        if (tau >= 1 && tau <= Tn){
            int row = tid >> 3, u = tid & 7;
            v4f g4 = *(const v4f*)(gatesc + row*GSS + 4*u);
            v4f bb = *(const v4f*)(b2s + 4*u);
            float gi = sigm(g4.x + bb.x);
            float gf = sigm(g4.y + bb.y);
            float gg = tanh_f(g4.z + bb.z);
            float go = sigm(g4.w + bb.w);
            float c  = c2s[tid];
            float cn = gf*c + gi*gg;
            float hn = go * tanh_f(cn);
            c2s[tid] = cn;
            hstage[tid] = (_Float16)hn;
        }
        if (tau >= 2 && tid < 64){
            float s = 0.f;
            #pragma unroll
            for (int u = 0; u < 8; ++u){
                float hv = headsc[tid*HSS + u] + bhs[u];
                s += fmaxf(hv, 0.f) * w2hs[u];
            }
            atomicAdd(&scores[(size_t)(tau - 2)*Bn + r0 + tid], s);
        }
        __syncthreads();

        // ===== phase G: publish h2(tau-1) (waves 0,1) + flag; no trailing barrier =====
        if (tau >= 1 && tau <= Tn && wv < 2){
            int slot = (tau + 3) & 3;            // (tau-1) & 3
            int row = tid >> 1, off = (tid & 1)*4;
            u64 v = *((const u64*)hstage + tid);
            __hip_atomic_store((u64*)(h2g + (size_t)slot*(Bn*Hn) + (size_t)(r0+row)*Hn + u0 + off),
                               v, __ATOMIC_RELAXED, __HIP_MEMORY_SCOPE_AGENT);
            __builtin_amdgcn_s_waitcnt(0);
            asm volatile("" ::: "memory");
            if (lane == 0)
                (void)__hip_atomic_fetch_add(&flags[c2idx], 1, __ATOMIC_RELAXED,
                                             __HIP_MEMORY_SCOPE_AGENT);
        }
        // next iteration's per-wave c1 poll (which requires this block's two c1
        // increments) gates re-entry; A1/H2l/hstage WARs are barrier-separated.
    }
}

// mixed[b] = scores.flat[b*1024 .. b*1024+1023]  (time-major flatten == contiguous)
__global__ __launch_bounds__(256)
void softmax_adv(const float* __restrict__ scores, float* __restrict__ out)
{
    const int b = blockIdx.x, tid = threadIdx.x;
    const int lane = tid & 63, wv = tid >> 6;
    __shared__ float red[4];
    const float4* sp = (const float4*)(scores + (size_t)b*1024);
    float4 v = sp[tid];
    float m = fmaxf(fmaxf(v.x, v.y), fmaxf(v.z, v.w));
    #pragma unroll
    for (int o = 32; o > 0; o >>= 1) m = fmaxf(m, __shfl_xor(m, o, 64));
    if (lane == 0) red[wv] = m;
    __syncthreads();
    m = fmaxf(fmaxf(red[0], red[1]), fmaxf(red[2], red[3]));
    __syncthreads();
    float e0 = __expf(v.x - m), e1 = __expf(v.y - m);
    float e2 = __expf(v.z - m), e3 = __expf(v.w - m);
    float s = e0 + e1 + e2 + e3;
    #pragma unroll
    for (int o = 32; o > 0; o >>= 1) s += __shfl_xor(s, o, 64);
    if (lane == 0) red[wv] = s;
    __syncthreads();
    s = red[0] + red[1] + red[2] + red[3];
    float inv = 1.0f / s;
    float4 o4; o4.x = e0*inv; o4.y = e1*inv; o4.z = e2*inv; o4.w = e3*inv;
    ((float4*)(out + (size_t)b*1024))[tid] = o4;
}

extern "C" void kernel_launch(void* const* d_in, const int* in_sizes, int n_in,
                              void* d_out, int out_size, void* d_ws, size_t ws_size,
                              hipStream_t stream)
{
    (void)in_sizes; (void)n_in; (void)out_size; (void)ws_size;
    const float* x      = (const float*)d_in[0];
    const float* w_ih0  = (const float*)d_in[1];
    const float* w_hh0  = (const float*)d_in[2];
    const float* b_ih0  = (const float*)d_in[3];
    const float* b_hh0  = (const float*)d_in[4];
    const float* w_ih1  = (const float*)d_in[5];
    const float* w_hh1  = (const float*)d_in[6];
    const float* b_ih1  = (const float*)d_in[7];
    const float* b_hh1  = (const float*)d_in[8];
    const float* adv_w1 = (const float*)d_in[9];
    const float* adv_b1 = (const float*)d_in[10];
    const float* adv_w2 = (const float*)d_in[11];
    // adv_w2 bias (d_in[12]) cancels in softmax — unused.

    float*    scores = (float*)((char*)d_ws + SCORES_OFF);
    _Float16* h1g    = (_Float16*)((char*)d_ws + H1G_OFF);
    _Float16* h2g    = (_Float16*)((char*)d_ws + H2G_OFF);
    int*      flags  = (int*)((char*)d_ws + FLAG_OFF);

    hipMemsetAsync(d_ws, 0, WS_USED, stream);
    hipFuncSetAttribute((const void*)lstm_pipe,
                        hipFuncAttributeMaxDynamicSharedMemorySize, LDS_TOTAL);

    hipLaunchKernelGGL(lstm_pipe, dim3(256), dim3(512), LDS_TOTAL, stream,
                       x, w_ih0, w_hh0, b_ih0, b_hh0, w_ih1, w_hh1, b_ih1, b_hh1,
                       adv_w1, adv_b1, adv_w2, scores, h1g, h2g, flags);
    hipLaunchKernelGGL(softmax_adv, dim3(512), dim3(256), 0, stream,
                       scores, (float*)d_out);
}

// Round 3
// 6765.568 us; speedup vs baseline: 4.9848x; 1.1946x over previous
//
#include <hip/hip_runtime.h>
#include <cstdint>
#include <cstddef>

// Problem constants
#define Tn 1024
#define Bn 512
#define Hn 256

// Partition: 256 blocks = 16 row-tiles (32 rows) x 16 unit-slices (16 units)
// LDS strides (fp16 elements)
#define H1S 264
#define H2S 264
#define W1S 280   // cols 0..9 x-w, 10..15 zero, 16..271 hh-w, pad
#define W2S 520   // cols 0..255 w_ih1, 256..511 w_hh1, pad
#define WHS 264
#define GWS 20    // per-wave gate scratch row stride (floats)

#define H1_OFF  0
#define H2_OFF  (H1_OFF + 32*H1S*2)      // 16896
#define XB_OFF  (H2_OFF + 32*H2S*2)      // 33792
#define W1_OFF  (XB_OFF + 2*32*16*2)     // 35840
#define W2_OFF  (W1_OFF + 64*W1S*2)      // 71680
#define WH_OFF  (W2_OFF + 64*W2S*2)      // 138240
#define GW_OFF  (WH_OFF + 16*WHS*2)      // 146688
#define B1_OFF  (GW_OFF + 8*16*GWS*4)    // 156928
#define B2_OFF  (B1_OFF + 64*4)
#define BH_OFF  (B2_OFF + 64*4)
#define W2H_OFF (BH_OFF + 16*4)
#define LDS_TOTAL (W2H_OFF + 16*4)       // 157568 B < 160 KiB -> 1 block/CU

// ws layout (bytes)
#define SCORES_OFF 0                      // [1024][512] f32 = 2MB
#define H1G_OFF  (2*1024*1024)            // 4 slots x [512][256] fp16 = 1MB
#define H2G_OFF  (3*1024*1024)            // 1MB
#define FLAG_OFF (4*1024*1024)            // tags1[16][16], tags2 at +256 ints
#define WS_USED  (4*1024*1024 + 4096)

typedef _Float16 v4h __attribute__((ext_vector_type(4)));
typedef float    v4f __attribute__((ext_vector_type(4)));
typedef unsigned long long u64;

__device__ inline float sigm(float x){ return 1.0f/(1.0f + __expf(-x)); }
__device__ inline float tanh_f(float x){ return 1.0f - 2.0f/(1.0f + __expf(2.0f*x)); }

__device__ inline void poll16(const int* tags, int tgt){
    int idx = threadIdx.x & 15;
    while (true){
        int t = __hip_atomic_load(&tags[idx], __ATOMIC_RELAXED, __HIP_MEMORY_SCOPE_AGENT);
        if (__ballot(t < tgt) == 0ull) break;
        __builtin_amdgcn_s_sleep(1);
    }
}

__global__ __launch_bounds__(512)
void lstm_pipe(const float* __restrict__ x,
               const float* __restrict__ w_ih0, const float* __restrict__ w_hh0,
               const float* __restrict__ b_ih0, const float* __restrict__ b_hh0,
               const float* __restrict__ w_ih1, const float* __restrict__ w_hh1,
               const float* __restrict__ b_ih1, const float* __restrict__ b_hh1,
               const float* __restrict__ adv_w1, const float* __restrict__ adv_b1,
               const float* __restrict__ adv_w2,
               float* __restrict__ scores, _Float16* __restrict__ h1g,
               _Float16* __restrict__ h2g, int* __restrict__ flags)
{
    extern __shared__ char smem[];
    _Float16* H1l = (_Float16*)(smem + H1_OFF);
    _Float16* H2l = (_Float16*)(smem + H2_OFF);
    _Float16* XBp = (_Float16*)(smem + XB_OFF);
    _Float16* W1l = (_Float16*)(smem + W1_OFF);
    _Float16* W2l = (_Float16*)(smem + W2_OFF);
    _Float16* WHl = (_Float16*)(smem + WH_OFF);
    float* gatesc = (float*)(smem + GW_OFF);
    float* b1s    = (float*)(smem + B1_OFF);
    float* b2s    = (float*)(smem + B2_OFF);
    float* bhs    = (float*)(smem + BH_OFF);
    float* w2hs   = (float*)(smem + W2H_OFF);

    const int tid  = threadIdx.x;
    const int lane = tid & 63;
    const int wv   = tid >> 6;
    const int ln15 = lane & 15;
    const int ln4  = lane >> 4;
    const int rt = blockIdx.x >> 4;        // 0..15 (32-row tile)
    const int us = blockIdx.x & 15;        // 0..15 (16-unit slice)
    const int r0 = rt * 32;
    const int u0 = us * 16;
    const int mt = wv & 1, nt = wv >> 1;   // MFMA tile grid 2(M) x 4(N)

    int* tags1 = flags;            // [16 rt][16 us]
    int* tags2 = flags + 256;

    // ---- one-time weight preload (gate-interleaved row order n = 4*u_local+g) ----
    for (int idx = tid; idx < 64*W1S; idx += 512){
        int n = idx / W1S, c = idx - n*W1S;
        int R = (n & 3)*256 + u0 + (n >> 2);
        float v = 0.f;
        if (c < 10) v = w_ih0[R*10 + c];
        else if (c >= 16 && c < 272) v = w_hh0[R*256 + (c-16)];
        W1l[idx] = (_Float16)v;
    }
    for (int idx = tid; idx < 64*W2S; idx += 512){
        int n = idx / W2S, c = idx - n*W2S;
        int R = (n & 3)*256 + u0 + (n >> 2);
        float v = (c < 256) ? w_ih1[R*256 + c] :
                  ((c < 512) ? w_hh1[R*256 + (c-256)] : 0.f);
        W2l[idx] = (_Float16)v;
    }
    for (int idx = tid; idx < 16*WHS; idx += 512){
        int n = idx / WHS, c = idx - n*WHS;
        float v = (c < 256) ? adv_w1[(u0+n)*256 + c] : 0.f;
        WHl[idx] = (_Float16)v;
    }
    if (tid < 64){
        int R = (tid & 3)*256 + u0 + (tid >> 2);
        b1s[tid] = b_ih0[R] + b_hh0[R];
        b2s[tid] = b_ih1[R] + b_hh1[R];
    }
    if (tid < 16){
        bhs[tid]  = adv_b1[u0 + tid];
        w2hs[tid] = adv_w2[u0 + tid];
    }
    // zero x double-buffer, then stage x(0)
    for (int idx = tid; idx < 1024; idx += 512) XBp[idx] = (_Float16)0.f;
    __syncthreads();
    if (tid < 32){
        const float* xp = x + ((size_t)(r0 + tid)*Tn + 0)*10;
        #pragma unroll
        for (int i = 0; i < 10; ++i) XBp[tid*16 + i] = (_Float16)xp[i];
    }
    __syncthreads();

    float c1 = 0.f, c2 = 0.f;              // cell state in registers
    float* gw = gatesc + wv*(16*GWS);      // wave-private gate scratch

    for (int tau = 0; tau <= Tn + 1; ++tau){
        // ===== phase A: poll c1; stage h1(tau-1); prefetch x(tau+1) to regs =====
        float xr[10];
        if (wv == 2 && lane < 32 && tau + 1 < Tn){
            const float* xp = x + ((size_t)(r0 + lane)*Tn + (tau+1))*10;
            #pragma unroll
            for (int i = 0; i < 10; ++i) xr[i] = xp[i];
        }
        if (tau >= 1 && tau <= Tn) poll16(tags1 + rt*16, tau);
        asm volatile("" ::: "memory");
        if (tau <= Tn){
            int slot = (tau + 3) & 3;      // (tau-1)&3
            int row = tid >> 4, seg = tid & 15;
            const u64* g = (const u64*)(h1g + (size_t)slot*(Bn*Hn) + (size_t)(r0+row)*Hn + seg*16);
            u64 a0 = __hip_atomic_load(g+0, __ATOMIC_RELAXED, __HIP_MEMORY_SCOPE_AGENT);
            u64 a1 = __hip_atomic_load(g+1, __ATOMIC_RELAXED, __HIP_MEMORY_SCOPE_AGENT);
            u64 a2 = __hip_atomic_load(g+2, __ATOMIC_RELAXED, __HIP_MEMORY_SCOPE_AGENT);
            u64 a3 = __hip_atomic_load(g+3, __ATOMIC_RELAXED, __HIP_MEMORY_SCOPE_AGENT);
            u64* l = (u64*)(H1l + row*H1S + seg*16);
            l[0]=a0; l[1]=a1; l[2]=a2; l[3]=a3;
        }
        __syncthreads();   // A

        // ===== phase B: poll c2 + issue h2 loads; G1(tau); EW1; publish h1 =====
        u64 r4[4];
        const bool have2 = (tau >= 1);
        if (tau >= 2) poll16(tags2 + rt*16, tau - 1);
        asm volatile("" ::: "memory");
        if (have2){
            int slot = (tau + 2) & 3;      // (tau-2)&3
            int row = tid >> 4, seg = tid & 15;
            const u64* g = (const u64*)(h2g + (size_t)slot*(Bn*Hn) + (size_t)(r0+row)*Hn + seg*16);
            r4[0] = __hip_atomic_load(g+0, __ATOMIC_RELAXED, __HIP_MEMORY_SCOPE_AGENT);
            r4[1] = __hip_atomic_load(g+1, __ATOMIC_RELAXED, __HIP_MEMORY_SCOPE_AGENT);
            r4[2] = __hip_atomic_load(g+2, __ATOMIC_RELAXED, __HIP_MEMORY_SCOPE_AGENT);
            r4[3] = __hip_atomic_load(g+3, __ATOMIC_RELAXED, __HIP_MEMORY_SCOPE_AGENT);
        }
        if (tau < Tn){
            v4f acc = {0.f,0.f,0.f,0.f};
            // k-tile 0: x part (double-buffered, 16 cols incl zero pad)
            {
                const _Float16* Ax = XBp + (tau & 1)*512 + (mt*16 + ln15)*16 + ln4*4;
                const _Float16* Bx = W1l + (nt*16 + ln15)*W1S + ln4*4;
                acc = __builtin_amdgcn_mfma_f32_16x16x16f16(*(const v4h*)Ax, *(const v4h*)Bx, acc, 0, 0, 0);
            }
            const _Float16* Ap = H1l + (mt*16 + ln15)*H1S + ln4*4;
            const _Float16* Bp = W1l + (nt*16 + ln15)*W1S + 16 + ln4*4;
            #pragma unroll
            for (int k = 0; k < 16; ++k)
                acc = __builtin_amdgcn_mfma_f32_16x16x16f16(*(const v4h*)(Ap + k*16),
                                                            *(const v4h*)(Bp + k*16), acc, 0, 0, 0);
            // wave-private EW (transpose via LDS, no barrier)
            #pragma unroll
            for (int r = 0; r < 4; ++r) gw[(ln4*4 + r)*GWS + ln15] = acc[r];
            asm volatile("s_waitcnt lgkmcnt(0)" ::: "memory");
            v4f g4 = *(const v4f*)(gw + ln15*GWS + ln4*4);
            v4f bb = *(const v4f*)(b1s + nt*16 + ln4*4);
            float gi = sigm(g4.x + bb.x), gf = sigm(g4.y + bb.y);
            float gg = tanh_f(g4.z + bb.z), go = sigm(g4.w + bb.w);
            c1 = gf*c1 + gi*gg;
            float hn = go * tanh_f(c1);
            // pack 4 units/row via shfl, publish from lanes ln4==0
            union { _Float16 h; unsigned short u; } cvt; cvt.h = (_Float16)hn;
            unsigned v32 = cvt.u;
            unsigned p16 = (unsigned)__shfl_xor((int)v32, 16, 64);
            unsigned lo32 = v32 | (p16 << 16);
            unsigned hi32 = (unsigned)__shfl_xor((int)lo32, 32, 64);
            if (ln4 == 0){
                u64 pk = (u64)lo32 | ((u64)hi32 << 32);
                __hip_atomic_store((u64*)(h1g + (size_t)(tau & 3)*(Bn*Hn)
                                   + (size_t)(r0 + mt*16 + ln15)*Hn + u0 + nt*4),
                                   pk, __ATOMIC_RELAXED, __HIP_MEMORY_SCOPE_AGENT);
            }
        }
        if (wv == 2 && lane < 32 && tau + 1 < Tn){
            _Float16* xd = XBp + ((tau+1) & 1)*512 + lane*16;
            #pragma unroll
            for (int i = 0; i < 10; ++i) xd[i] = (_Float16)xr[i];
        }
        if (have2){
            int row = tid >> 4, seg = tid & 15;
            u64* l = (u64*)(H2l + row*H2S + seg*16);
            l[0]=r4[0]; l[1]=r4[1]; l[2]=r4[2]; l[3]=r4[3];
        }
        __syncthreads();   // B (drains h1 publishes; makes H2l visible)
        if (tau < Tn && tid == 0)
            __hip_atomic_store(&tags1[rt*16 + us], tau + 1, __ATOMIC_RELAXED, __HIP_MEMORY_SCOPE_AGENT);

        // ===== phase C: G2(tau-1) + head(tau-2); EW2; publish h2 =====
        if (tau >= 1 && tau <= Tn){
            v4f acc = {0.f,0.f,0.f,0.f};
            const _Float16* Ap1 = H1l + (mt*16 + ln15)*H1S + ln4*4;
            const _Float16* Ap2 = H2l + (mt*16 + ln15)*H2S + ln4*4;
            const _Float16* Bp  = W2l + (nt*16 + ln15)*W2S + ln4*4;
            #pragma unroll
            for (int k = 0; k < 16; ++k)
                acc = __builtin_amdgcn_mfma_f32_16x16x16f16(*(const v4h*)(Ap1 + k*16),
                                                            *(const v4h*)(Bp + k*16), acc, 0, 0, 0);
            #pragma unroll
            for (int k = 0; k < 16; ++k)
                acc = __builtin_amdgcn_mfma_f32_16x16x16f16(*(const v4h*)(Ap2 + k*16),
                                                            *(const v4h*)(Bp + 256 + k*16), acc, 0, 0, 0);
            #pragma unroll
            for (int r = 0; r < 4; ++r) gw[(ln4*4 + r)*GWS + ln15] = acc[r];
            asm volatile("s_waitcnt lgkmcnt(0)" ::: "memory");
            v4f g4 = *(const v4f*)(gw + ln15*GWS + ln4*4);
            v4f bb = *(const v4f*)(b2s + nt*16 + ln4*4);
            float gi = sigm(g4.x + bb.x), gf = sigm(g4.y + bb.y);
            float gg = tanh_f(g4.z + bb.z), go = sigm(g4.w + bb.w);
            c2 = gf*c2 + gi*gg;
            float hn = go * tanh_f(c2);
            union { _Float16 h; unsigned short u; } cvt; cvt.h = (_Float16)hn;
            unsigned v32 = cvt.u;
            unsigned p16 = (unsigned)__shfl_xor((int)v32, 16, 64);
            unsigned lo32 = v32 | (p16 << 16);
            unsigned hi32 = (unsigned)__shfl_xor((int)lo32, 32, 64);
            if (ln4 == 0){
                u64 pk = (u64)lo32 | ((u64)hi32 << 32);
                __hip_atomic_store((u64*)(h2g + (size_t)((tau + 3) & 3)*(Bn*Hn)
                                   + (size_t)(r0 + mt*16 + ln15)*Hn + u0 + nt*4),
                                   pk, __ATOMIC_RELAXED, __HIP_MEMORY_SCOPE_AGENT);
            }
        }
        if (tau >= 2 && wv >= 6){
            int mth = wv & 1;
            v4f acc = {0.f,0.f,0.f,0.f};
            const _Float16* Ap = H2l + (mth*16 + ln15)*H2S + ln4*4;
            const _Float16* Bp = WHl + ln15*WHS + ln4*4;
            #pragma unroll
            for (int k = 0; k < 16; ++k)
                acc = __builtin_amdgcn_mfma_f32_16x16x16f16(*(const v4h*)(Ap + k*16),
                                                            *(const v4h*)(Bp + k*16), acc, 0, 0, 0);
            float bh = bhs[ln15], w2 = w2hs[ln15];
            float t0 = fmaxf(acc[0] + bh, 0.f) * w2;
            float t1 = fmaxf(acc[1] + bh, 0.f) * w2;
            float t2 = fmaxf(acc[2] + bh, 0.f) * w2;
            float t3 = fmaxf(acc[3] + bh, 0.f) * w2;
            #pragma unroll
            for (int m = 1; m <= 8; m <<= 1){
                t0 += __shfl_xor(t0, m, 64);
                t1 += __shfl_xor(t1, m, 64);
                t2 += __shfl_xor(t2, m, 64);
                t3 += __shfl_xor(t3, m, 64);
            }
            if (ln15 == 0){
                float* sp = scores + (size_t)(tau - 2)*Bn + r0 + mth*16 + ln4*4;
                atomicAdd(sp + 0, t0);
                atomicAdd(sp + 1, t1);
                atomicAdd(sp + 2, t2);
                atomicAdd(sp + 3, t3);
            }
        }
        __syncthreads();   // C (drains h2 publishes)
        if (tau >= 1 && tau <= Tn && tid == 0)
            __hip_atomic_store(&tags2[rt*16 + us], tau, __ATOMIC_RELAXED, __HIP_MEMORY_SCOPE_AGENT);
    }
}

// mixed[b] = scores.flat[b*1024 .. b*1024+1023]  (time-major flatten == contiguous)
__global__ __launch_bounds__(256)
void softmax_adv(const float* __restrict__ scores, float* __restrict__ out)
{
    const int b = blockIdx.x, tid = threadIdx.x;
    const int lane = tid & 63, wv = tid >> 6;
    __shared__ float red[4];
    const float4* sp = (const float4*)(scores + (size_t)b*1024);
    float4 v = sp[tid];
    float m = fmaxf(fmaxf(v.x, v.y), fmaxf(v.z, v.w));
    #pragma unroll
    for (int o = 32; o > 0; o >>= 1) m = fmaxf(m, __shfl_xor(m, o, 64));
    if (lane == 0) red[wv] = m;
    __syncthreads();
    m = fmaxf(fmaxf(red[0], red[1]), fmaxf(red[2], red[3]));
    __syncthreads();
    float e0 = __expf(v.x - m), e1 = __expf(v.y - m);
    float e2 = __expf(v.z - m), e3 = __expf(v.w - m);
    float s = e0 + e1 + e2 + e3;
    #pragma unroll
    for (int o = 32; o > 0; o >>= 1) s += __shfl_xor(s, o, 64);
    if (lane == 0) red[wv] = s;
    __syncthreads();
    s = red[0] + red[1] + red[2] + red[3];
    float inv = 1.0f / s;
    float4 o4; o4.x = e0*inv; o4.y = e1*inv; o4.z = e2*inv; o4.w = e3*inv;
    ((float4*)(out + (size_t)b*1024))[tid] = o4;
}

extern "C" void kernel_launch(void* const* d_in, const int* in_sizes, int n_in,
                              void* d_out, int out_size, void* d_ws, size_t ws_size,
                              hipStream_t stream)
{
    (void)in_sizes; (void)n_in; (void)out_size; (void)ws_size;
    const float* x      = (const float*)d_in[0];
    const float* w_ih0  = (const float*)d_in[1];
    const float* w_hh0  = (const float*)d_in[2];
    const float* b_ih0  = (const float*)d_in[3];
    const float* b_hh0  = (const float*)d_in[4];
    const float* w_ih1  = (const float*)d_in[5];
    const float* w_hh1  = (const float*)d_in[6];
    const float* b_ih1  = (const float*)d_in[7];
    const float* b_hh1  = (const float*)d_in[8];
    const float* adv_w1 = (const float*)d_in[9];
    const float* adv_b1 = (const float*)d_in[10];
    const float* adv_w2 = (const float*)d_in[11];
    // adv_w2 bias (d_in[12]) cancels in softmax — unused.

    float*    scores = (float*)((char*)d_ws + SCORES_OFF);
    _Float16* h1g    = (_Float16*)((char*)d_ws + H1G_OFF);
    _Float16* h2g    = (_Float16*)((char*)d_ws + H2G_OFF);
    int*      flags  = (int*)((char*)d_ws + FLAG_OFF);

    hipMemsetAsync(d_ws, 0, WS_USED, stream);
    hipFuncSetAttribute((const void*)lstm_pipe,
                        hipFuncAttributeMaxDynamicSharedMemorySize, LDS_TOTAL);

    hipLaunchKernelGGL(lstm_pipe, dim3(256), dim3(512), LDS_TOTAL, stream,
                       x, w_ih0, w_hh0, b_ih0, b_hh0, w_ih1, w_hh1, b_ih1, b_hh1,
                       adv_w1, adv_b1, adv_w2, scores, h1g, h2g, flags);
    hipLaunchKernelGGL(softmax_adv, dim3(512), dim3(256), 0, stream,
                       scores, (float*)d_out);
}